// Round 8
// baseline (1277.078 us; speedup 1.0000x reference)
//
#include <hip/hip_runtime.h>
#include <hip/hip_bf16.h>

#define BGRAPH 16384
#define NPG 9
#define RANK 512
#define EPER 12
#define NNODE (BGRAPH*NPG)      // 147456
#define GPB 4                   // graphs per block
#define BM (GPB*NPG)            // 36 real rows per block
#define BMP 48                  // padded rows for MFMA (3 x 16)
#define BK 64                   // K-chunk (two MFMA k-steps)
#define NKC (RANK/BK)           // 8
#define LEPS 1e-5f

typedef unsigned short u16;
typedef unsigned int u32;
typedef __attribute__((ext_vector_type(8))) short s16x8;
typedef __attribute__((ext_vector_type(4))) float f32x4;

static __device__ __forceinline__ float bf2f(u16 u){
    union { u32 i; float f; } v; v.i = ((u32)u) << 16; return v.f;
}
static __device__ __forceinline__ u16 f2bf(float f){
    union { float f; u32 i; } v; v.f = f;
    u32 r = v.i + 0x7FFFu + ((v.i >> 16) & 1u);   // RNE
    return (u16)(r >> 16);
}

// ---- W repack into B-fragment order (bf16) ---- (verified R4/R6)
// Wp[((kb*32 + c)*64 + l)*8 + j] = W[kb*32 + (l>>4)*8 + j][c*16 + (l&15)]
__global__ void k_repack(const float* __restrict__ Ws, u16* __restrict__ Wp){
    int t = blockIdx.x*256 + threadIdx.x;          // 3*512*512 total
    int layer = t >> 18;
    int r = t & 262143;
    int j = r & 7, l = (r>>3)&63, c = (r>>9)&31, kb = r>>14;
    int k = kb*32 + (l>>4)*8 + j;
    int col = c*16 + (l&15);
    Wp[t] = f2bf(Ws[(size_t)layer*262144 + (size_t)k*512 + col]);
}

// ---- fully fused: embed + 3x(dense-A aggregate -> MFMA -> bias+LN+ReLU) + out ----
// GPB=4: LDS ~44.7 KB -> 2 blocks/CU (vs R4's 1), branchless dense aggregation.
__launch_bounds__(512, 4)
__global__ void k_fused(const int* __restrict__ feat, const int* __restrict__ src,
                        const int* __restrict__ dst, const float* __restrict__ emb,
                        const u16* __restrict__ Wp,
                        const float* __restrict__ bs, const float* __restrict__ gam,
                        const float* __restrict__ bet,
                        const float* __restrict__ w_out, const float* __restrict__ b_out,
                        float* __restrict__ out)
{
    // h[row][col] bf16, 16B slot s stored at s^(row&7)  (verified swizzle rule)
    __shared__ __align__(16) u16 h[BM*RANK];       // 36864 B
    __shared__ __align__(16) u16 m_t[BMP*BK];      // 6144 B; epilogue overlays red_s/red_q
    __shared__ float A_s[GPB*81];                  // 1296 B
    __shared__ float s_mu[BM], s_rs[BM];           // 288 B
    __shared__ int   s_flags[2];

    const int t = threadIdx.x;
    const int lane = t & 63;
    const int w = t >> 6;
    const int g0 = blockIdx.x * GPB;
    const int row0 = g0 * NPG;

    // ---- dtype detection (int32 vs int64), fault-proof (verified R4/R6) ----
    if (t == 0){
        int o = feat[1]|feat[3]|feat[5]|feat[7]|feat[9]|feat[11]|feat[13]|feat[15];
        s_flags[0] = (o == 0);                         // feat is int64
        int v = src[EPER*BGRAPH - 1];                  // int32: >=147447; int64 high word: 0
        s_flags[1] = (v < (BGRAPH-1)*NPG);             // src/dst are int64
    }
    __syncthreads();
    const int f64 = s_flags[0], i64 = s_flags[1];

    // ---- per-graph dense A[d][s] = inorm[d]*onorm[s]*mult(s->d), threads 0..3 ----
    if (t < GPB){
        int g = g0 + t;
        int sl[EPER], dl[EPER];
        #pragma unroll
        for (int j=0;j<EPER;j++){
            int e = g*EPER + j;
            int sv = (i64 ? src[2*e] : src[e]) - g*NPG;
            int dv = (i64 ? dst[2*e] : dst[e]) - g*NPG;
            sl[j] = sv<0?0:(sv>8?8:sv);
            dl[j] = dv<0?0:(dv>8?8:dv);
        }
        float onorm[NPG], inorm[NPG];
        #pragma unroll
        for (int i=0;i<NPG;i++){
            int co=0, ci=0;
            #pragma unroll
            for (int j=0;j<EPER;j++){ co += (sl[j]==i); ci += (dl[j]==i); }
            onorm[i] = rsqrtf((float)(co>0?co:1));
            inorm[i] = rsqrtf((float)(ci>0?ci:1));
        }
        #pragma unroll
        for (int d=0; d<NPG; d++){
            #pragma unroll
            for (int s=0; s<NPG; s++){
                int c = 0;
                #pragma unroll
                for (int j=0;j<EPER;j++) c += (dl[j]==d) & (sl[j]==s);
                A_s[t*81 + d*9 + s] = inorm[d]*onorm[s]*(float)c;
            }
        }
    }

    // ---- embedding gather -> h (bf16, swizzled) ----
    for (int idx = t; idx < BM*64; idx += 512){
        int row = idx >> 6, slot = idx & 63;
        int n = row0 + row;
        int f = f64 ? feat[2*n] : feat[n];
        f = (f<0)?0:(f>5?5:f);
        const float4* e = reinterpret_cast<const float4*>(emb + (size_t)f*RANK + slot*8);
        float4 a = e[0], b = e[1];
        uint4 o;
        o.x = (u32)f2bf(a.x) | ((u32)f2bf(a.y)<<16);
        o.y = (u32)f2bf(a.z) | ((u32)f2bf(a.w)<<16);
        o.z = (u32)f2bf(b.x) | ((u32)f2bf(b.y)<<16);
        o.w = (u32)f2bf(b.z) | ((u32)f2bf(b.w)<<16);
        *reinterpret_cast<uint4*>(h + row*RANK + (slot^(row&7))*8) = o;
    }

    const int lr = lane & 15, hi = lane >> 4;

    for (int L=0; L<3; L++){
        const u16* WpL = Wp + (size_t)L*262144;
        f32x4 acc[3][4];
        #pragma unroll
        for (int r=0;r<3;r++)
            #pragma unroll
            for (int cc=0;cc<4;cc++)
                #pragma unroll
                for (int q=0;q<4;q++) acc[r][cc][q] = 0.f;

        __syncthreads();   // h ready (embed or previous epilogue)

        for (int kc=0; kc<NKC; kc++){
            // a) dense aggregation: 36 rows x 32 colpairs, thread-linear, branchless
            for (int o = t; o < BM*32; o += 512){
                int row = o >> 5, cp = o & 31;
                int g = (row * 57) >> 9;               // row/9 for row<36
                int d = row - g*9;
                int base = g*9;
                const float* Arow = &A_s[g*81 + d*9];
                int k = kc*BK + cp*2;
                float a0=0.f, a1=0.f;
                #pragma unroll
                for (int s=0;s<9;s++){
                    int sr = base + s;
                    u32 v = *reinterpret_cast<const u32*>(
                        h + sr*RANK + ((k>>3)^(sr&7))*8 + (k&7));
                    float wA = Arow[s];
                    a0 += wA * bf2f((u16)(v & 0xffffu));
                    a1 += wA * bf2f((u16)(v >> 16));
                }
                u32 ov = (u32)f2bf(a0) | ((u32)f2bf(a1)<<16);
                *reinterpret_cast<u32*>(m_t + row*BK + ((cp>>2)^(row&7))*8 + ((cp*2)&7)) = ov;
            }
            __syncthreads();
            // b) MFMA: wave w owns cols [w*64, w*64+64); padded rows 36-47 garbage but unused
            #pragma unroll
            for (int kk=0; kk<2; kk++){
                s16x8 af[3];
                #pragma unroll
                for (int r=0;r<3;r++){
                    int rowa = r*16 + lr;
                    af[r] = *reinterpret_cast<const s16x8*>(
                        m_t + rowa*BK + ((kk*4+hi)^(rowa&7))*8);
                }
                #pragma unroll
                for (int cc=0;cc<4;cc++){
                    s16x8 bf = *reinterpret_cast<const s16x8*>(
                        WpL + (size_t)((((kc*2+kk)*32 + (w*4+cc))*64 + lane)*8));
                    #pragma unroll
                    for (int r=0;r<3;r++)
                        acc[r][cc] = __builtin_amdgcn_mfma_f32_16x16x32_bf16(af[r], bf, acc[r][cc], 0, 0, 0);
                }
            }
            __syncthreads();
        }

        // ---- epilogue: bias + LN + ReLU -> h (bf16, swizzled) ----
        const float* bias = bs + L*RANK;
        const float* gmp  = gam + L*RANK;
        const float* btp  = bet + L*RANK;
        float b4[4], g4[4], bt4[4];
        #pragma unroll
        for (int cc=0;cc<4;cc++){
            int col = w*64 + cc*16 + lr;
            b4[cc] = bias[col]; g4[cc] = gmp[col]; bt4[cc] = btp[col];
        }
        #pragma unroll
        for (int r=0;r<3;r++)
            #pragma unroll
            for (int cc=0;cc<4;cc++)
                #pragma unroll
                for (int q=0;q<4;q++) acc[r][cc][q] += b4[cc];

        float* red_s = reinterpret_cast<float*>(m_t);   // 1152 B
        float* red_q = red_s + BM*8;                    // 1152 B (fits in 6144)
        #pragma unroll
        for (int r=0;r<3;r++){
            #pragma unroll
            for (int q=0;q<4;q++){
                int row = r*16 + hi*4 + q;
                float s=0.f, qq=0.f;
                #pragma unroll
                for (int cc=0;cc<4;cc++){ float x = acc[r][cc][q]; s += x; qq += x*x; }
                #pragma unroll
                for (int mm=1;mm<16;mm<<=1){ s += __shfl_xor(s, mm, 64); qq += __shfl_xor(qq, mm, 64); }
                if (lr==0 && row < BM){ red_s[row*8+w]=s; red_q[row*8+w]=qq; }
            }
        }
        __syncthreads();
        if (t < BM){
            float s=0.f, qq=0.f;
            #pragma unroll
            for (int i=0;i<8;i++){ s += red_s[t*8+i]; qq += red_q[t*8+i]; }
            float mu = s * (1.f/RANK);
            float var = qq*(1.f/RANK) - mu*mu;
            s_mu[t] = mu; s_rs[t] = rsqrtf(var + LEPS);
        }
        __syncthreads();
        #pragma unroll
        for (int r=0;r<3;r++){
            #pragma unroll
            for (int q=0;q<4;q++){
                int row = r*16 + hi*4 + q;
                if (row < BM){
                    float mu = s_mu[row], rs = s_rs[row];
                    #pragma unroll
                    for (int cc=0;cc<4;cc++){
                        int col = w*64 + cc*16 + lr;
                        float y = (acc[r][cc][q]-mu)*rs*g4[cc] + bt4[cc];
                        y = fmaxf(y, 0.f);
                        h[row*RANK + ((col>>3)^(row&7))*8 + (col&7)] = f2bf(y);
                    }
                }
            }
        }
    }
    __syncthreads();

    // ---- final dot: graph g (=wave id < 4), first node row = g*9 ----
    if (w < GPB){
        int row = w*NPG;
        s16x8 hv = *reinterpret_cast<const s16x8*>(h + row*RANK + (lane^(row&7))*8);
        const float4* wv = reinterpret_cast<const float4*>(w_out + lane*8);
        float4 w0 = wv[0], w1 = wv[1];
        float a = bf2f((u16)hv[0])*w0.x + bf2f((u16)hv[1])*w0.y
                + bf2f((u16)hv[2])*w0.z + bf2f((u16)hv[3])*w0.w
                + bf2f((u16)hv[4])*w1.x + bf2f((u16)hv[5])*w1.y
                + bf2f((u16)hv[6])*w1.z + bf2f((u16)hv[7])*w1.w;
        #pragma unroll
        for (int mm=1;mm<64;mm<<=1) a += __shfl_xor(a, mm, 64);
        if (lane==0) out[g0 + w] = a + b_out[0];
    }
}

extern "C" void kernel_launch(void* const* d_in, const int* in_sizes, int n_in,
                              void* d_out, int out_size, void* d_ws, size_t ws_size,
                              hipStream_t stream){
    (void)in_sizes; (void)n_in; (void)out_size; (void)ws_size;
    const int*   feat  = (const int*)d_in[0];
    const int*   src   = (const int*)d_in[1];
    const int*   dst   = (const int*)d_in[2];
    const float* emb   = (const float*)d_in[3];
    const float* Ws    = (const float*)d_in[4];
    const float* bs    = (const float*)d_in[5];
    const float* gam   = (const float*)d_in[6];
    const float* bet   = (const float*)d_in[7];
    const float* w_out = (const float*)d_in[8];
    const float* b_out = (const float*)d_in[9];
    float* out = (float*)d_out;

    u16* Wp = (u16*)d_ws;   // 1.5 MB — proven-safe ws footprint (R4/R6)

    k_repack<<<dim3(3*RANK*RANK/256), dim3(256), 0, stream>>>(Ws, Wp);
    k_fused<<<dim3(BGRAPH/GPB), dim3(512), 0, stream>>>(feat, src, dst, emb, Wp,
        bs, gam, bet, w_out, b_out, out);
}

// Round 9
// 1029.999 us; speedup vs baseline: 1.2399x; 1.2399x over previous
//
#include <hip/hip_runtime.h>
#include <hip/hip_bf16.h>

#define BGRAPH 16384
#define NPG 9
#define RANK 512
#define EPER 12
#define GPB 4                   // graphs per block, one 16-row tile each
#define LEPS 1e-5f

typedef unsigned short u16;
typedef unsigned int u32;
typedef __attribute__((ext_vector_type(8))) short s16x8;
typedef __attribute__((ext_vector_type(4))) float f32x4;

static __device__ __forceinline__ float bf2f(u16 u){
    union { u32 i; float f; } v; v.i = ((u32)u) << 16; return v.f;
}
static __device__ __forceinline__ u16 f2bf(float f){
    union { float f; u32 i; } v; v.f = f;
    u32 r = v.i + 0x7FFFu + ((v.i >> 16) & 1u);   // RNE
    return (u16)(r >> 16);
}

// ---- W repack into B-fragment order (bf16) ---- (verified R4/R6/R8)
// Wp[((kb*32 + c)*64 + l)*8 + j] = W[kb*32 + (l>>4)*8 + j][c*16 + (l&15)]
__global__ void k_repack(const float* __restrict__ Ws, u16* __restrict__ Wp){
    int t = blockIdx.x*256 + threadIdx.x;          // 3*512*512 total
    int layer = t >> 18;
    int r = t & 262143;
    int j = r & 7, l = (r>>3)&63, c = (r>>9)&31, kb = r>>14;
    int k = kb*32 + (l>>4)*8 + j;
    int col = c*16 + (l&15);
    Wp[t] = f2bf(Ws[(size_t)layer*262144 + (size_t)k*512 + col]);
}

// ---- fused: embed + 2x(GEMM -> A-mix(MFMA) -> bias+LN+ReLU) + agg+GEMM+LN+dot ----
__launch_bounds__(512, 4)
__global__ void k_fused(const int* __restrict__ feat, const int* __restrict__ src,
                        const int* __restrict__ dst, const float* __restrict__ emb,
                        const u16* __restrict__ Wp,
                        const float* __restrict__ bs, const float* __restrict__ gam,
                        const float* __restrict__ bet,
                        const float* __restrict__ w_out, const float* __restrict__ b_out,
                        float* __restrict__ out)
{
    // h[row][col] bf16; graph r at rows r*16 .. r*16+8, rows +9..+15 zero pad.
    // 16B slot s of row stored at s^(row&7)  (verified swizzle rule)
    __shared__ __align__(16) u16 h[64*RANK];       // 65536 B
    __shared__ float A_s[GPB*81];                  // 1296 B
    __shared__ float red_s[36*8], red_q[36*8];     // 2304 B
    __shared__ float s_mu[36], s_rs[36];           // 288 B
    __shared__ int   s_flags[2];

    const int t = threadIdx.x;
    const int lane = t & 63;
    const int w = t >> 6;
    const int lr = lane & 15, hi = lane >> 4;
    const int g0 = blockIdx.x * GPB;
    const int row0 = g0 * NPG;

    // ---- dtype detection (verified R4/R6/R8) ----
    if (t == 0){
        int o = feat[1]|feat[3]|feat[5]|feat[7]|feat[9]|feat[11]|feat[13]|feat[15];
        s_flags[0] = (o == 0);                         // feat is int64
        int v = src[EPER*BGRAPH - 1];
        s_flags[1] = (v < (BGRAPH-1)*NPG);             // src/dst are int64
    }
    __syncthreads();
    const int f64 = s_flags[0], i64 = s_flags[1];

    // ---- per-graph dense A[d][s] (verified R8) ----
    if (t < GPB){
        int g = g0 + t;
        int sl[EPER], dl[EPER];
        #pragma unroll
        for (int j=0;j<EPER;j++){
            int e = g*EPER + j;
            int sv = (i64 ? src[2*e] : src[e]) - g*NPG;
            int dv = (i64 ? dst[2*e] : dst[e]) - g*NPG;
            sl[j] = sv<0?0:(sv>8?8:sv);
            dl[j] = dv<0?0:(dv>8?8:dv);
        }
        float onorm[NPG], inorm[NPG];
        #pragma unroll
        for (int i=0;i<NPG;i++){
            int co=0, ci=0;
            #pragma unroll
            for (int j=0;j<EPER;j++){ co += (sl[j]==i); ci += (dl[j]==i); }
            onorm[i] = rsqrtf((float)(co>0?co:1));
            inorm[i] = rsqrtf((float)(ci>0?ci:1));
        }
        #pragma unroll
        for (int d=0; d<NPG; d++){
            #pragma unroll
            for (int s=0; s<NPG; s++){
                int c = 0;
                #pragma unroll
                for (int j=0;j<EPER;j++) c += (dl[j]==d) & (sl[j]==s);
                A_s[t*81 + d*9 + s] = inorm[d]*onorm[s]*(float)c;
            }
        }
    }

    // ---- embed -> h real rows (bf16, swizzled) ----
    for (int idx = t; idx < 36*64; idx += 512){
        int rl = idx >> 6, slot = idx & 63;
        int r = (rl*57) >> 9;                      // rl/9, exact for rl<36
        int d = rl - r*9;
        int lrow = r*16 + d;
        int n = row0 + rl;
        int f = f64 ? feat[2*n] : feat[n];
        f = (f<0)?0:(f>5?5:f);
        const float4* e = reinterpret_cast<const float4*>(emb + (size_t)f*RANK + slot*8);
        float4 a = e[0], b = e[1];
        uint4 o;
        o.x = (u32)f2bf(a.x) | ((u32)f2bf(a.y)<<16);
        o.y = (u32)f2bf(a.z) | ((u32)f2bf(a.w)<<16);
        o.z = (u32)f2bf(b.x) | ((u32)f2bf(b.y)<<16);
        o.w = (u32)f2bf(b.z) | ((u32)f2bf(b.w)<<16);
        *reinterpret_cast<uint4*>(h + lrow*RANK + ((slot^(lrow&7))*8)) = o;
    }
    // ---- zero pad rows (stay zero forever) ----
    for (int idx = t; idx < 28*64; idx += 512){
        int pr = idx >> 6, slot = idx & 63;
        int r = (pr*37) >> 8;                      // pr/7, exact for pr<28
        int d0 = pr - r*7;
        int lrow = r*16 + 9 + d0;
        uint4 zz; zz.x=0; zz.y=0; zz.z=0; zz.w=0;
        *reinterpret_cast<uint4*>(h + lrow*RANK + ((slot^(lrow&7))*8)) = zz;
    }
    __syncthreads();

    // ================= layers 1 & 2 =================
    for (int L=0; L<2; L++){
        const u16* WpL = Wp + (size_t)L*262144;
        f32x4 acc[4][4];
        #pragma unroll
        for (int r=0;r<4;r++)
            #pragma unroll
            for (int cc=0;cc<4;cc++)
                #pragma unroll
                for (int q=0;q<4;q++) acc[r][cc][q] = 0.f;

        // ---- z = h @ W : pure MFMA K-loop, no barriers ----
        #pragma unroll 4
        for (int ks=0; ks<16; ks++){
            s16x8 af[4];
            #pragma unroll
            for (int r=0;r<4;r++){
                int rowa = r*16 + lr;
                af[r] = *reinterpret_cast<const s16x8*>(
                    h + rowa*RANK + (((ks*4+hi)^(rowa&7))*8));
            }
            #pragma unroll
            for (int cc=0;cc<4;cc++){
                s16x8 bf = *reinterpret_cast<const s16x8*>(
                    WpL + (size_t)(((ks*32 + (w*4+cc))*64 + lane)*8));
                #pragma unroll
                for (int r=0;r<4;r++)
                    acc[r][cc] = __builtin_amdgcn_mfma_f32_16x16x32_bf16(af[r], bf, acc[r][cc], 0, 0, 0);
            }
        }

        const float* bias = bs + L*RANK;
        const float* gmp  = gam + L*RANK;
        const float* btp  = bet + L*RANK;
        float b4[4], g4[4], bt4[4];
        #pragma unroll
        for (int cc=0;cc<4;cc++){
            int col = w*64 + cc*16 + lr;
            b4[cc] = bias[col]; g4[cc] = gmp[col]; bt4[cc] = btp[col];
        }

        // ---- m = A @ z via MFMA (A, z both split hi+lo bf16) + bias ----
        #pragma unroll
        for (int r=0;r<4;r++){
            s16x8 Ah, Al;                          // A-operand: row=lr(d), k=hi*8+j(s)
            #pragma unroll
            for (int j=0;j<8;j++){
                int s = hi*8 + j;
                float av = (lr<9 && s<9) ? A_s[r*81 + lr*9 + s] : 0.f;
                u16 ah = f2bf(av);
                Ah[j] = (short)ah;
                Al[j] = (short)f2bf(av - bf2f(ah));
            }
            #pragma unroll
            for (int cc=0;cc<4;cc++){
                f32x4 z = acc[r][cc];
                // z rows s: C/D layout row=(hi_z*4+q). Rearrange to B-frag k=hi*8+j.
                float sa0=__shfl_xor(z[0],16), sa1=__shfl_xor(z[1],16), sa2=__shfl_xor(z[2],16), sa3=__shfl_xor(z[3],16);
                float sb0=__shfl_xor(z[0],32), sb1=__shfl_xor(z[1],32), sb2=__shfl_xor(z[2],32), sb3=__shfl_xor(z[3],32);
                float sc0=__shfl_xor(z[0],48), sc1=__shfl_xor(z[1],48), sc2=__shfl_xor(z[2],48), sc3=__shfl_xor(z[3],48);
                float x0 = hi==0 ? z[0] : (hi==1 ? sc0 : 0.f);
                float x1 = hi==0 ? z[1] : (hi==1 ? sc1 : 0.f);
                float x2 = hi==0 ? z[2] : (hi==1 ? sc2 : 0.f);
                float x3 = hi==0 ? z[3] : (hi==1 ? sc3 : 0.f);
                float x4 = hi==0 ? sa0 : (hi==1 ? sb0 : 0.f);
                float x5 = hi==0 ? sa1 : (hi==1 ? sb1 : 0.f);
                float x6 = hi==0 ? sa2 : (hi==1 ? sb2 : 0.f);
                float x7 = hi==0 ? sa3 : (hi==1 ? sb3 : 0.f);
                s16x8 zh, zl;
                float xs[8] = {x0,x1,x2,x3,x4,x5,x6,x7};
                #pragma unroll
                for (int j=0;j<8;j++){
                    u16 hh = f2bf(xs[j]);
                    zh[j] = (short)hh;
                    zl[j] = (short)f2bf(xs[j] - bf2f(hh));
                }
                f32x4 mix; mix[0]=0.f; mix[1]=0.f; mix[2]=0.f; mix[3]=0.f;
                mix = __builtin_amdgcn_mfma_f32_16x16x32_bf16(Al, zh, mix, 0, 0, 0);
                mix = __builtin_amdgcn_mfma_f32_16x16x32_bf16(Ah, zl, mix, 0, 0, 0);
                mix = __builtin_amdgcn_mfma_f32_16x16x32_bf16(Ah, zh, mix, 0, 0, 0);
                #pragma unroll
                for (int q=0;q<4;q++) mix[q] += b4[cc];
                acc[r][cc] = mix;
            }
        }

        // ---- LN over feature dim (cross-wave) ----
        #pragma unroll
        for (int r=0;r<4;r++){
            #pragma unroll
            for (int q=0;q<4;q++){
                int d = hi*4 + q;
                float s=0.f, qq=0.f;
                #pragma unroll
                for (int cc=0;cc<4;cc++){ float x = acc[r][cc][q]; s += x; qq += x*x; }
                #pragma unroll
                for (int mm=1;mm<16;mm<<=1){ s += __shfl_xor(s, mm); qq += __shfl_xor(qq, mm); }
                if (lr==0 && d<9){ red_s[(r*9+d)*8+w]=s; red_q[(r*9+d)*8+w]=qq; }
            }
        }
        __syncthreads();
        if (t < 36){
            float s=0.f, qq=0.f;
            #pragma unroll
            for (int i=0;i<8;i++){ s += red_s[t*8+i]; qq += red_q[t*8+i]; }
            float mu = s * (1.f/RANK);
            float var = qq*(1.f/RANK) - mu*mu;
            s_mu[t] = mu; s_rs[t] = rsqrtf(var + LEPS);
        }
        __syncthreads();
        #pragma unroll
        for (int r=0;r<4;r++){
            #pragma unroll
            for (int q=0;q<4;q++){
                int d = hi*4 + q;
                if (d < 9){
                    float mu = s_mu[r*9+d], rs = s_rs[r*9+d];
                    int row = r*16 + d;
                    #pragma unroll
                    for (int cc=0;cc<4;cc++){
                        int col = w*64 + cc*16 + lr;
                        float y = (acc[r][cc][q]-mu)*rs*g4[cc] + bt4[cc];
                        y = fmaxf(y, 0.f);
                        h[row*RANK + (((col>>3)^(row&7))*8) + (col&7)] = f2bf(y);
                    }
                }
            }
        }
        __syncthreads();
    }

    // ================= layer 3: only node 0 per graph =================
    // magg[g] = A[g][0,:] @ h2   (aggregate FIRST, then GEMM on 4 rows)
    float mgA[2], mgB[2]; int rr_[2], kk_[2];
    #pragma unroll
    for (int it=0; it<2; it++){
        int o = t + it*512;                        // 1024 tasks: 4 graphs x 256 colpairs
        int r = o >> 8, cp = o & 255, k2 = cp*2;
        float a=0.f, b=0.f;
        #pragma unroll
        for (int s=0;s<9;s++){
            int srow = r*16 + s;
            u32 v = *reinterpret_cast<const u32*>(
                h + srow*RANK + (((k2>>3)^(srow&7))*8) + (k2&7));
            float wA = A_s[r*81 + s];              // d=0 row of A
            a += wA * bf2f((u16)(v & 0xffffu));
            b += wA * bf2f((u16)(v >> 16));
        }
        mgA[it]=a; mgB[it]=b; rr_[it]=r; kk_[it]=k2;
    }
    __syncthreads();                               // all h reads done
    #pragma unroll
    for (int it=0; it<2; it++){
        int r = rr_[it], k2 = kk_[it];
        u32 ov = (u32)f2bf(mgA[it]) | ((u32)f2bf(mgB[it])<<16);
        *reinterpret_cast<u32*>(h + r*RANK + (((k2>>3)^(r&7))*8) + (k2&7)) = ov;
    }
    for (int idx = t; idx < 12*64; idx += 512){    // zero rows 4..15 of tile 0
        int rowz = 4 + (idx>>6), slot = idx & 63;
        uint4 zz; zz.x=0; zz.y=0; zz.z=0; zz.w=0;
        *reinterpret_cast<uint4*>(h + rowz*RANK + ((slot^(rowz&7))*8)) = zz;
    }
    __syncthreads();

    // z3 = magg @ W3 : single-tile GEMM
    const u16* Wp3 = Wp + (size_t)2*262144;
    f32x4 acc3[4];
    #pragma unroll
    for (int cc=0;cc<4;cc++)
        #pragma unroll
        for (int q=0;q<4;q++) acc3[cc][q] = 0.f;
    #pragma unroll 4
    for (int ks=0; ks<16; ks++){
        s16x8 af0 = *reinterpret_cast<const s16x8*>(
            h + lr*RANK + (((ks*4+hi)^(lr&7))*8));
        #pragma unroll
        for (int cc=0;cc<4;cc++){
            s16x8 bf = *reinterpret_cast<const s16x8*>(
                Wp3 + (size_t)(((ks*32 + (w*4+cc))*64 + lane)*8));
            acc3[cc] = __builtin_amdgcn_mfma_f32_16x16x32_bf16(af0, bf, acc3[cc], 0, 0, 0);
        }
    }
    float b3[4], g3[4], bt3[4];
    #pragma unroll
    for (int cc=0;cc<4;cc++){
        int col = w*64 + cc*16 + lr;
        b3[cc] = bs[2*RANK+col]; g3[cc] = gam[2*RANK+col]; bt3[cc] = bet[2*RANK+col];
    }
    #pragma unroll
    for (int cc=0;cc<4;cc++)
        #pragma unroll
        for (int q=0;q<4;q++) acc3[cc][q] += b3[cc];

    if (hi == 0){                                  // rows 0-3 = graphs 0-3
        #pragma unroll
        for (int q=0;q<4;q++){
            float s=0.f, qq=0.f;
            #pragma unroll
            for (int cc=0;cc<4;cc++){ float x = acc3[cc][q]; s += x; qq += x*x; }
            #pragma unroll
            for (int mm=1;mm<16;mm<<=1){ s += __shfl_xor(s, mm); qq += __shfl_xor(qq, mm); }
            if (lr==0){ red_s[q*8+w]=s; red_q[q*8+w]=qq; }
        }
    }
    __syncthreads();
    if (t < 4){
        float s=0.f, qq=0.f;
        #pragma unroll
        for (int i=0;i<8;i++){ s += red_s[t*8+i]; qq += red_q[t*8+i]; }
        float mu = s * (1.f/RANK);
        float var = qq*(1.f/RANK) - mu*mu;
        s_mu[t] = mu; s_rs[t] = rsqrtf(var + LEPS);
    }
    __syncthreads();
    if (hi == 0){
        float part[4] = {0.f,0.f,0.f,0.f};
        #pragma unroll
        for (int cc=0;cc<4;cc++){
            int col = w*64 + cc*16 + lr;
            float wv = w_out[col];
            #pragma unroll
            for (int q=0;q<4;q++){
                float y = (acc3[cc][q]-s_mu[q])*s_rs[q]*g3[cc] + bt3[cc];
                y = fmaxf(y, 0.f);
                part[q] += y*wv;
            }
        }
        #pragma unroll
        for (int q=0;q<4;q++){
            float p = part[q];
            #pragma unroll
            for (int mm=1;mm<16;mm<<=1) p += __shfl_xor(p, mm);
            if (lr==0) red_s[q*8+w] = p;
        }
    }
    __syncthreads();
    if (t < 4){
        float sum = 0.f;
        #pragma unroll
        for (int i=0;i<8;i++) sum += red_s[t*8+i];
        out[g0 + t] = sum + b_out[0];
    }
}

extern "C" void kernel_launch(void* const* d_in, const int* in_sizes, int n_in,
                              void* d_out, int out_size, void* d_ws, size_t ws_size,
                              hipStream_t stream){
    (void)in_sizes; (void)n_in; (void)out_size; (void)ws_size;
    const int*   feat  = (const int*)d_in[0];
    const int*   src   = (const int*)d_in[1];
    const int*   dst   = (const int*)d_in[2];
    const float* emb   = (const float*)d_in[3];
    const float* Ws    = (const float*)d_in[4];
    const float* bs    = (const float*)d_in[5];
    const float* gam   = (const float*)d_in[6];
    const float* bet   = (const float*)d_in[7];
    const float* w_out = (const float*)d_in[8];
    const float* b_out = (const float*)d_in[9];
    float* out = (float*)d_out;

    u16* Wp = (u16*)d_ws;   // 1.5 MB — proven-safe ws footprint (R4/R6/R8)

    k_repack<<<dim3(3*RANK*RANK/256), dim3(256), 0, stream>>>(Ws, Wp);
    k_fused<<<dim3(BGRAPH/GPB), dim3(512), 0, stream>>>(feat, src, dst, emb, Wp,
        bs, gam, bet, w_out, b_out, out);
}

// Round 10
// 788.771 us; speedup vs baseline: 1.6191x; 1.3058x over previous
//
#include <hip/hip_runtime.h>
#include <hip/hip_bf16.h>

#define BGRAPH 16384
#define NPG 9
#define RANK 512
#define EPER 12
#define NNODE (BGRAPH*NPG)      // 147456
#define GPB 7                   // graphs per block -> 63 real rows of 64
#define NROW 63
#define NBLK ((BGRAPH + GPB - 1)/GPB)   // 2341
#define LEPS 1e-5f

typedef unsigned short u16;
typedef unsigned int u32;
typedef __attribute__((ext_vector_type(8))) short s16x8;
typedef __attribute__((ext_vector_type(4))) float f32x4;

static __device__ __forceinline__ float bf2f(u16 u){
    union { u32 i; float f; } v; v.i = ((u32)u) << 16; return v.f;
}
static __device__ __forceinline__ u16 f2bf(float f){
    union { float f; u32 i; } v; v.f = f;
    u32 r = v.i + 0x7FFFu + ((v.i >> 16) & 1u);   // RNE
    return (u16)(r >> 16);
}

// ---- W repack into B-fragment order (bf16) ---- (verified R4/R6/R8/R9)
// Wp[((kb*32 + c)*64 + l)*8 + j] = W[kb*32 + (l>>4)*8 + j][c*16 + (l&15)]
__global__ void k_repack(const float* __restrict__ Ws, u16* __restrict__ Wp){
    int t = blockIdx.x*256 + threadIdx.x;          // 3*512*512 total
    int layer = t >> 18;
    int r = t & 262143;
    int j = r & 7, l = (r>>3)&63, c = (r>>9)&31, kb = r>>14;
    int k = kb*32 + (l>>4)*8 + j;
    int col = c*16 + (l&15);
    Wp[t] = f2bf(Ws[(size_t)layer*262144 + (size_t)k*512 + col]);
}

// ---- fused: embed + 2x(GEMM -> exact-C mix -> bias+LN+ReLU) + layer3 + dot ----
__launch_bounds__(512, 4)
__global__ void k_fused(const int* __restrict__ feat, const int* __restrict__ src,
                        const int* __restrict__ dst, const float* __restrict__ emb,
                        const u16* __restrict__ Wp,
                        const float* __restrict__ bs, const float* __restrict__ gam,
                        const float* __restrict__ bet,
                        const float* __restrict__ w_out, const float* __restrict__ b_out,
                        float* __restrict__ out)
{
    // h[row][col] bf16; rows 0..62 = nodes row0..row0+62, row 63 zero.
    // 16B slot s of row stored at s^(row&7)  (verified swizzle rule)
    __shared__ __align__(16) u16 h[64*RANK];           // 65536 B
    __shared__ __align__(16) u16 Cpack[8*64*8];        // 8192 B  (C64 frags, exact bf16)
    __shared__ float s_C[GPB*81];                      // 2268 B  (edge counts, f32)
    __shared__ float s_onr[64], s_inr[64];             // 512 B   (row-indexed norms)
    __shared__ float red_s[NROW*8], red_q[NROW*8];     // 4032 B
    __shared__ float s_mu[NROW], s_rs[NROW];           // 504 B
    __shared__ int   s_flags[2];

    const int t = threadIdx.x;
    const int lane = t & 63;
    const int w = t >> 6;
    const int lr = lane & 15, hi = lane >> 4;
    const int g0 = blockIdx.x * GPB;
    const int row0 = g0 * NPG;

    // ---- dtype detection (verified R4/R6/R8/R9) ----
    if (t == 0){
        int o = feat[1]|feat[3]|feat[5]|feat[7]|feat[9]|feat[11]|feat[13]|feat[15];
        s_flags[0] = (o == 0);
        int v = src[EPER*BGRAPH - 1];
        s_flags[1] = (v < (BGRAPH-1)*NPG);
    }
    __syncthreads();
    const int f64 = s_flags[0], i64 = s_flags[1];

    // ---- per-graph counts + norms (row-indexed) ----
    if (t < GPB){
        int g = g0 + t; if (g > BGRAPH-1) g = BGRAPH-1;
        int sl[EPER], dl[EPER];
        #pragma unroll
        for (int j=0;j<EPER;j++){
            int e = g*EPER + j;
            int sv = (i64 ? src[2*e] : src[e]) - g*NPG;
            int dv = (i64 ? dst[2*e] : dst[e]) - g*NPG;
            sl[j] = sv<0?0:(sv>8?8:sv);
            dl[j] = dv<0?0:(dv>8?8:dv);
        }
        #pragma unroll
        for (int i=0;i<NPG;i++){
            int co=0, ci=0;
            #pragma unroll
            for (int j=0;j<EPER;j++){ co += (sl[j]==i); ci += (dl[j]==i); }
            s_onr[t*NPG+i] = rsqrtf((float)(co>0?co:1));
            s_inr[t*NPG+i] = rsqrtf((float)(ci>0?ci:1));
        }
        #pragma unroll
        for (int d=0; d<NPG; d++){
            #pragma unroll
            for (int s=0; s<NPG; s++){
                int c = 0;
                #pragma unroll
                for (int j=0;j<EPER;j++) c += (dl[j]==d) & (sl[j]==s);
                s_C[t*81 + d*9 + s] = (float)c;
            }
        }
    }
    if (t == 0){ s_onr[63] = 0.f; s_inr[63] = 0.f; }

    // ---- embed rows 0..62, zero row 63 ----
    for (int idx = t; idx < 64*64; idx += 512){
        int row = idx >> 6, slot = idx & 63;
        uint4 o; o.x=0; o.y=0; o.z=0; o.w=0;
        if (row < NROW){
            int n = row0 + row; if (n > NNODE-1) n = NNODE-1;
            int f = f64 ? feat[2*n] : feat[n];
            f = (f<0)?0:(f>5?5:f);
            const float4* e = reinterpret_cast<const float4*>(emb + (size_t)f*RANK + slot*8);
            float4 a = e[0], b = e[1];
            o.x = (u32)f2bf(a.x) | ((u32)f2bf(a.y)<<16);
            o.y = (u32)f2bf(a.z) | ((u32)f2bf(a.w)<<16);
            o.z = (u32)f2bf(b.x) | ((u32)f2bf(b.y)<<16);
            o.w = (u32)f2bf(b.z) | ((u32)f2bf(b.w)<<16);
        }
        *reinterpret_cast<uint4*>(h + row*RANK + ((slot^(row&7))*8)) = o;
    }
    __syncthreads();

    // ---- build Cpack: frag for (stripe, ks) -> C64[stripe*16+lr][ks*32+(j>>2)*16+hi*4+(j&3)]
    // one 16B entry per thread; linear index == t (since (t>>6)*64 + (t&63) == t)
    {
        int le = t & 63;
        int lre = le & 15, hie = le >> 4;
        int stripe = t >> 7, ksb = (t >> 6) & 1;
        int row = stripe*16 + lre;
        int gr = (row*57) >> 9, dr = row - gr*9;
        short cv[8];
        #pragma unroll
        for (int j=0;j<8;j++){
            int col = ksb*32 + ((j>>2)<<4) + hie*4 + (j&3);
            int gc = (col*57) >> 9, sc = col - gc*9;
            int ok = (row < NROW) & (col < NROW) & (gr == gc);
            int cidx = gr*81 + dr*9 + sc; if (cidx > GPB*81-1) cidx = 0;
            float val = ok ? s_C[cidx] : 0.f;
            cv[j] = (short)f2bf(val);                  // exact: small ints
        }
        s16x8 cfr;
        #pragma unroll
        for (int j=0;j<8;j++) cfr[j] = cv[j];
        *reinterpret_cast<s16x8*>(Cpack + t*8) = cfr;
    }
    __syncthreads();

    // ================= layers 1 & 2 =================
    for (int L=0; L<2; L++){
        const u16* WpL = Wp + (size_t)L*262144;
        f32x4 acc[4][4];
        #pragma unroll
        for (int r=0;r<4;r++)
            #pragma unroll
            for (int cc=0;cc<4;cc++)
                #pragma unroll
                for (int q=0;q<4;q++) acc[r][cc][q] = 0.f;

        // ---- z = h @ W : pure MFMA K-loop ----
        #pragma unroll 4
        for (int ks=0; ks<16; ks++){
            s16x8 af[4];
            #pragma unroll
            for (int r=0;r<4;r++){
                int rowa = r*16 + lr;
                af[r] = *reinterpret_cast<const s16x8*>(
                    h + rowa*RANK + (((ks*4+hi)^(rowa&7))*8));
            }
            #pragma unroll
            for (int cc=0;cc<4;cc++){
                s16x8 bf = *reinterpret_cast<const s16x8*>(
                    WpL + (size_t)(((ks*32 + (w*4+cc))*64 + lane)*8));
                #pragma unroll
                for (int r=0;r<4;r++)
                    acc[r][cc] = __builtin_amdgcn_mfma_f32_16x16x32_bf16(af[r], bf, acc[r][cc], 0, 0, 0);
            }
        }

        // ---- pre-scale rows by out_norm (z' = D_out z), in place ----
        #pragma unroll
        for (int r=0;r<4;r++){
            #pragma unroll
            for (int q=0;q<4;q++){
                float so = s_onr[r*16 + hi*4 + q];
                #pragma unroll
                for (int cc=0;cc<4;cc++) acc[r][cc][q] *= so;
            }
        }

        // ---- pack zf[8]: zf[cc*2+ks] elem j = z'[ks*32+(j>>2)*16+hi*4+(j&3)][cc*16+lr]
        //      = acc[ks*2+(j>>2)][cc][j&3]  (lane-local, NO shuffles) ----
        s16x8 zf[8];
        #pragma unroll
        for (int cc=0;cc<4;cc++){
            #pragma unroll
            for (int ks=0;ks<2;ks++){
                s16x8 z;
                z[0] = (short)f2bf(acc[ks*2  ][cc][0]);
                z[1] = (short)f2bf(acc[ks*2  ][cc][1]);
                z[2] = (short)f2bf(acc[ks*2  ][cc][2]);
                z[3] = (short)f2bf(acc[ks*2  ][cc][3]);
                z[4] = (short)f2bf(acc[ks*2+1][cc][0]);
                z[5] = (short)f2bf(acc[ks*2+1][cc][1]);
                z[6] = (short)f2bf(acc[ks*2+1][cc][2]);
                z[7] = (short)f2bf(acc[ks*2+1][cc][3]);
                zf[cc*2+ks] = z;
            }
        }

        // ---- mix: m = C @ z' (C exact bf16), overwrite acc ----
        #pragma unroll
        for (int ro=0; ro<4; ro++){
            s16x8 cf0 = *reinterpret_cast<const s16x8*>(Cpack + ((ro*2+0)*64 + lane)*8);
            s16x8 cf1 = *reinterpret_cast<const s16x8*>(Cpack + ((ro*2+1)*64 + lane)*8);
            #pragma unroll
            for (int cc=0;cc<4;cc++){
                f32x4 m; m[0]=0.f; m[1]=0.f; m[2]=0.f; m[3]=0.f;
                m = __builtin_amdgcn_mfma_f32_16x16x32_bf16(cf1, zf[cc*2+1], m, 0, 0, 0);
                m = __builtin_amdgcn_mfma_f32_16x16x32_bf16(cf0, zf[cc*2+0], m, 0, 0, 0);
                acc[ro][cc] = m;
            }
        }

        // ---- post-scale by in_norm + bias ----
        const float* bias = bs + L*RANK;
        const float* gmp  = gam + L*RANK;
        const float* btp  = bet + L*RANK;
        float b4[4], g4[4], bt4[4];
        #pragma unroll
        for (int cc=0;cc<4;cc++){
            int col = w*64 + cc*16 + lr;
            b4[cc] = bias[col]; g4[cc] = gmp[col]; bt4[cc] = btp[col];
        }
        #pragma unroll
        for (int ro=0;ro<4;ro++){
            #pragma unroll
            for (int q=0;q<4;q++){
                float si = s_inr[ro*16 + hi*4 + q];
                #pragma unroll
                for (int cc=0;cc<4;cc++) acc[ro][cc][q] = acc[ro][cc][q]*si + b4[cc];
            }
        }

        // ---- LN over feature dim ----
        #pragma unroll
        for (int r=0;r<4;r++){
            #pragma unroll
            for (int q=0;q<4;q++){
                int row = r*16 + hi*4 + q;
                float s=0.f, qq=0.f;
                #pragma unroll
                for (int cc=0;cc<4;cc++){ float x = acc[r][cc][q]; s += x; qq += x*x; }
                #pragma unroll
                for (int mm=1;mm<16;mm<<=1){ s += __shfl_xor(s, mm); qq += __shfl_xor(qq, mm); }
                if (lr==0 && row < NROW){ red_s[row*8+w]=s; red_q[row*8+w]=qq; }
            }
        }
        __syncthreads();
        if (t < NROW){
            float s=0.f, qq=0.f;
            #pragma unroll
            for (int i=0;i<8;i++){ s += red_s[t*8+i]; qq += red_q[t*8+i]; }
            float mu = s * (1.f/RANK);
            float var = qq*(1.f/RANK) - mu*mu;
            s_mu[t] = mu; s_rs[t] = rsqrtf(var + LEPS);
        }
        __syncthreads();
        #pragma unroll
        for (int r=0;r<4;r++){
            #pragma unroll
            for (int q=0;q<4;q++){
                int row = r*16 + hi*4 + q;
                if (row < NROW){
                    float mu = s_mu[row], rs = s_rs[row];
                    #pragma unroll
                    for (int cc=0;cc<4;cc++){
                        int col = w*64 + cc*16 + lr;
                        float y = (acc[r][cc][q]-mu)*rs*g4[cc] + bt4[cc];
                        y = fmaxf(y, 0.f);
                        h[row*RANK + (((col>>3)^(row&7))*8) + (col&7)] = f2bf(y);
                    }
                }
            }
        }
        __syncthreads();
    }

    // ================= layer 3: only node 0 per graph =================
    // magg[g][col] = inorm0 * sum_s C[g][0][s]*onorm[s]*h2[g*9+s][col]
    float mgA[4], mgB[4];
    #pragma unroll
    for (int it=0; it<4; it++){
        int task = t + it*512;
        float a0=0.f, a1=0.f;
        if (task < GPB*256){
            int r = task >> 8, k2 = (task & 255)*2;
            #pragma unroll
            for (int s=0;s<9;s++){
                int srow = r*9 + s;
                u32 v = *reinterpret_cast<const u32*>(
                    h + srow*RANK + (((k2>>3)^(srow&7))*8) + (k2&7));
                float wA = s_C[r*81 + s] * s_onr[srow];
                a0 += wA * bf2f((u16)(v & 0xffffu));
                a1 += wA * bf2f((u16)(v >> 16));
            }
            float fin = s_inr[r*9];
            a0 *= fin; a1 *= fin;
        }
        mgA[it] = a0; mgB[it] = a1;
    }
    __syncthreads();                               // all h reads done
    #pragma unroll
    for (int it=0; it<4; it++){
        int task = t + it*512;
        if (task < GPB*256){
            int r = task >> 8, k2 = (task & 255)*2;
            u32 ov = (u32)f2bf(mgA[it]) | ((u32)f2bf(mgB[it])<<16);
            *reinterpret_cast<u32*>(h + r*RANK + (((k2>>3)^(r&7))*8) + (k2&7)) = ov;
        }
    }
    for (int idx = t; idx < 9*64; idx += 512){     // zero rows 7..15
        int rowz = 7 + (idx>>6), slot = idx & 63;
        uint4 zz; zz.x=0; zz.y=0; zz.z=0; zz.w=0;
        *reinterpret_cast<uint4*>(h + rowz*RANK + ((slot^(rowz&7))*8)) = zz;
    }
    __syncthreads();

    // z3 = magg @ W3 : single-tile GEMM (rows 0..6 real, 7..15 zero)
    const u16* Wp3 = Wp + (size_t)2*262144;
    f32x4 acc3[4];
    #pragma unroll
    for (int cc=0;cc<4;cc++)
        #pragma unroll
        for (int q=0;q<4;q++) acc3[cc][q] = 0.f;
    #pragma unroll 4
    for (int ks=0; ks<16; ks++){
        s16x8 af0 = *reinterpret_cast<const s16x8*>(
            h + lr*RANK + (((ks*4+hi)^(lr&7))*8));
        #pragma unroll
        for (int cc=0;cc<4;cc++){
            s16x8 bf = *reinterpret_cast<const s16x8*>(
                Wp3 + (size_t)(((ks*32 + (w*4+cc))*64 + lane)*8));
            acc3[cc] = __builtin_amdgcn_mfma_f32_16x16x32_bf16(af0, bf, acc3[cc], 0, 0, 0);
        }
    }
    float b3[4], g3[4], bt3[4];
    #pragma unroll
    for (int cc=0;cc<4;cc++){
        int col = w*64 + cc*16 + lr;
        b3[cc] = bs[2*RANK+col]; g3[cc] = gam[2*RANK+col]; bt3[cc] = bet[2*RANK+col];
    }
    #pragma unroll
    for (int cc=0;cc<4;cc++)
        #pragma unroll
        for (int q=0;q<4;q++) acc3[cc][q] += b3[cc];

    // LN over rows 0..6
    #pragma unroll
    for (int q=0;q<4;q++){
        int row = hi*4 + q;
        float s=0.f, qq=0.f;
        #pragma unroll
        for (int cc=0;cc<4;cc++){ float x = acc3[cc][q]; s += x; qq += x*x; }
        #pragma unroll
        for (int mm=1;mm<16;mm<<=1){ s += __shfl_xor(s, mm); qq += __shfl_xor(qq, mm); }
        if (lr==0 && row < GPB){ red_s[row*8+w]=s; red_q[row*8+w]=qq; }
    }
    __syncthreads();
    if (t < GPB){
        float s=0.f, qq=0.f;
        #pragma unroll
        for (int i=0;i<8;i++){ s += red_s[t*8+i]; qq += red_q[t*8+i]; }
        float mu = s * (1.f/RANK);
        float var = qq*(1.f/RANK) - mu*mu;
        s_mu[t] = mu; s_rs[t] = rsqrtf(var + LEPS);
    }
    __syncthreads();
    // dot with w_out
    #pragma unroll
    for (int q=0;q<4;q++){
        int row = hi*4 + q;
        float p = 0.f;
        if (row < GPB){
            float mu = s_mu[row], rs = s_rs[row];
            #pragma unroll
            for (int cc=0;cc<4;cc++){
                int col = w*64 + cc*16 + lr;
                float y = (acc3[cc][q]-mu)*rs*g3[cc] + bt3[cc];
                y = fmaxf(y, 0.f);
                p += y * w_out[col];
            }
        }
        #pragma unroll
        for (int mm=1;mm<16;mm<<=1) p += __shfl_xor(p, mm);
        if (lr==0 && row < GPB) red_s[row*8+w] = p;
    }
    __syncthreads();
    if (t < GPB){
        float sum = 0.f;
        #pragma unroll
        for (int i=0;i<8;i++) sum += red_s[t*8+i];
        int g = g0 + t;
        if (g < BGRAPH) out[g] = sum + b_out[0];
    }
}

extern "C" void kernel_launch(void* const* d_in, const int* in_sizes, int n_in,
                              void* d_out, int out_size, void* d_ws, size_t ws_size,
                              hipStream_t stream){
    (void)in_sizes; (void)n_in; (void)out_size; (void)ws_size;
    const int*   feat  = (const int*)d_in[0];
    const int*   src   = (const int*)d_in[1];
    const int*   dst   = (const int*)d_in[2];
    const float* emb   = (const float*)d_in[3];
    const float* Ws    = (const float*)d_in[4];
    const float* bs    = (const float*)d_in[5];
    const float* gam   = (const float*)d_in[6];
    const float* bet   = (const float*)d_in[7];
    const float* w_out = (const float*)d_in[8];
    const float* b_out = (const float*)d_in[9];
    float* out = (float*)d_out;

    u16* Wp = (u16*)d_ws;   // 1.5 MB — proven-safe ws footprint

    k_repack<<<dim3(3*RANK*RANK/256), dim3(256), 0, stream>>>(Ws, Wp);
    k_fused<<<dim3(NBLK), dim3(512), 0, stream>>>(feat, src, dst, emb, Wp,
        bs, gam, bet, w_out, b_out, out);
}

// Round 13
// 547.044 us; speedup vs baseline: 2.3345x; 1.4419x over previous
//
#include <hip/hip_runtime.h>
#include <hip/hip_bf16.h>

#define BGRAPH 16384
#define NPG 9
#define RANK 512
#define EPER 12
#define NNODE (BGRAPH*NPG)      // 147456
#define GPB 7                   // graphs per block -> 63 real rows of 64
#define NROW 63
#define NBLK ((BGRAPH + GPB - 1)/GPB)   // 2341
#define LEPS 1e-5f

typedef unsigned short u16;
typedef unsigned int u32;
typedef __attribute__((ext_vector_type(8))) short s16x8;
typedef __attribute__((ext_vector_type(4))) float f32x4;

static __device__ __forceinline__ float bf2f(u16 u){
    union { u32 i; float f; } v; v.i = ((u32)u) << 16; return v.f;
}
static __device__ __forceinline__ u16 f2bf(float f){
    union { float f; u32 i; } v; v.f = f;
    u32 r = v.i + 0x7FFFu + ((v.i >> 16) & 1u);   // RNE
    return (u16)(r >> 16);
}

// ---- W repack into B-fragment order (bf16) ---- (verified R4..R10)
// Wp[((kb*32 + c)*64 + l)*8 + j] = W[kb*32 + (l>>4)*8 + j][c*16 + (l&15)]
__global__ void k_repack(const float* __restrict__ Ws, u16* __restrict__ Wp){
    int t = blockIdx.x*256 + threadIdx.x;          // 3*512*512 total
    int layer = t >> 18;
    int r = t & 262143;
    int j = r & 7, l = (r>>3)&63, c = (r>>9)&31, kb = r>>14;
    int k = kb*32 + (l>>4)*8 + j;
    int col = c*16 + (l&15);
    Wp[t] = f2bf(Ws[(size_t)layer*262144 + (size_t)k*512 + col]);
}

// ---- fused: embed + 2x(GEMM -> exact-C mix -> bias+LN+ReLU) + layer3 + dot ----
// launch_bounds(512,2): 256-VGPR budget -> NO SPILLS (R10: 128-cap caused 1.1GB
// of scratch traffic = the entire runtime). Occupancy follows actual usage.
__launch_bounds__(512, 2)
__global__ void k_fused(const int* __restrict__ feat, const int* __restrict__ src,
                        const int* __restrict__ dst, const float* __restrict__ emb,
                        const u16* __restrict__ Wp,
                        const float* __restrict__ bs, const float* __restrict__ gam,
                        const float* __restrict__ bet,
                        const float* __restrict__ w_out, const float* __restrict__ b_out,
                        float* __restrict__ out)
{
    // h[row][col] bf16; rows 0..62 = nodes row0..row0+62, row 63 zero.
    // 16B slot s of row stored at s^(row&7)  (verified swizzle rule)
    __shared__ __align__(16) u16 h[64*RANK];           // 65536 B
    __shared__ __align__(16) u16 Cpack[8*64*8];        // 8192 B  (C64 frags, exact bf16)
    __shared__ float s_C[GPB*81];                      // 2268 B  (edge counts, f32)
    __shared__ float s_onr[64], s_inr[64];             // 512 B   (row-indexed norms)
    __shared__ float red_s[NROW*8], red_q[NROW*8];     // 4032 B
    __shared__ float s_mu[NROW], s_rs[NROW];           // 504 B
    __shared__ int   s_flags[2];

    const int t = threadIdx.x;
    const int lane = t & 63;
    const int w = t >> 6;
    const int lr = lane & 15, hi = lane >> 4;
    const int g0 = blockIdx.x * GPB;
    const int row0 = g0 * NPG;

    // ---- dtype detection (verified R4..R10) ----
    if (t == 0){
        int o = feat[1]|feat[3]|feat[5]|feat[7]|feat[9]|feat[11]|feat[13]|feat[15];
        s_flags[0] = (o == 0);
        int v = src[EPER*BGRAPH - 1];
        s_flags[1] = (v < (BGRAPH-1)*NPG);
    }
    __syncthreads();
    const int f64 = s_flags[0], i64 = s_flags[1];

    // ---- per-graph counts + norms (row-indexed) ----
    if (t < GPB){
        int g = g0 + t; if (g > BGRAPH-1) g = BGRAPH-1;
        int sl[EPER], dl[EPER];
        #pragma unroll
        for (int j=0;j<EPER;j++){
            int e = g*EPER + j;
            int sv = (i64 ? src[2*e] : src[e]) - g*NPG;
            int dv = (i64 ? dst[2*e] : dst[e]) - g*NPG;
            sl[j] = sv<0?0:(sv>8?8:sv);
            dl[j] = dv<0?0:(dv>8?8:dv);
        }
        #pragma unroll
        for (int i=0;i<NPG;i++){
            int co=0, ci=0;
            #pragma unroll
            for (int j=0;j<EPER;j++){ co += (sl[j]==i); ci += (dl[j]==i); }
            s_onr[t*NPG+i] = rsqrtf((float)(co>0?co:1));
            s_inr[t*NPG+i] = rsqrtf((float)(ci>0?ci:1));
        }
        #pragma unroll
        for (int d=0; d<NPG; d++){
            #pragma unroll
            for (int s=0; s<NPG; s++){
                int c = 0;
                #pragma unroll
                for (int j=0;j<EPER;j++) c += (dl[j]==d) & (sl[j]==s);
                s_C[t*81 + d*9 + s] = (float)c;
            }
        }
    }
    if (t == 0){ s_onr[63] = 0.f; s_inr[63] = 0.f; }

    // ---- embed rows 0..62, zero row 63 ----
    for (int idx = t; idx < 64*64; idx += 512){
        int row = idx >> 6, slot = idx & 63;
        uint4 o; o.x=0; o.y=0; o.z=0; o.w=0;
        if (row < NROW){
            int n = row0 + row; if (n > NNODE-1) n = NNODE-1;
            int f = f64 ? feat[2*n] : feat[n];
            f = (f<0)?0:(f>5?5:f);
            const float4* e = reinterpret_cast<const float4*>(emb + (size_t)f*RANK + slot*8);
            float4 a = e[0], b = e[1];
            o.x = (u32)f2bf(a.x) | ((u32)f2bf(a.y)<<16);
            o.y = (u32)f2bf(a.z) | ((u32)f2bf(a.w)<<16);
            o.z = (u32)f2bf(b.x) | ((u32)f2bf(b.y)<<16);
            o.w = (u32)f2bf(b.z) | ((u32)f2bf(b.w)<<16);
        }
        *reinterpret_cast<uint4*>(h + row*RANK + ((slot^(row&7))*8)) = o;
    }
    __syncthreads();

    // ---- build Cpack: frag for (stripe, ks) -> C64[stripe*16+lr][ks*32+(j>>2)*16+hi*4+(j&3)]
    {
        int le = t & 63;
        int lre = le & 15, hie = le >> 4;
        int stripe = t >> 7, ksb = (t >> 6) & 1;
        int row = stripe*16 + lre;
        int gr = (row*57) >> 9, dr = row - gr*9;
        s16x8 cfr;
        #pragma unroll
        for (int j=0;j<8;j++){
            int col = ksb*32 + ((j>>2)<<4) + hie*4 + (j&3);
            int gc = (col*57) >> 9, sc = col - gc*9;
            int ok = (row < NROW) & (col < NROW) & (gr == gc);
            int cidx = gr*81 + dr*9 + sc; if (cidx > GPB*81-1) cidx = 0;
            float val = ok ? s_C[cidx] : 0.f;
            cfr[j] = (short)f2bf(val);                 // exact: small ints
        }
        *reinterpret_cast<s16x8*>(Cpack + t*8) = cfr;
    }
    __syncthreads();

    // ================= layers 1 & 2 =================
    for (int L=0; L<2; L++){
        const u16* WpL = Wp + (size_t)L*262144;
        f32x4 acc[4][4];
        #pragma unroll
        for (int r=0;r<4;r++)
            #pragma unroll
            for (int cc=0;cc<4;cc++)
                #pragma unroll
                for (int q=0;q<4;q++) acc[r][cc][q] = 0.f;

        // ---- z = h @ W : pure MFMA K-loop ----
        #pragma unroll 4
        for (int ks=0; ks<16; ks++){
            s16x8 af[4];
            #pragma unroll
            for (int r=0;r<4;r++){
                int rowa = r*16 + lr;
                af[r] = *reinterpret_cast<const s16x8*>(
                    h + rowa*RANK + (((ks*4+hi)^(rowa&7))*8));
            }
            #pragma unroll
            for (int cc=0;cc<4;cc++){
                s16x8 bf = *reinterpret_cast<const s16x8*>(
                    WpL + (size_t)(((ks*32 + (w*4+cc))*64 + lane)*8));
                #pragma unroll
                for (int r=0;r<4;r++)
                    acc[r][cc] = __builtin_amdgcn_mfma_f32_16x16x32_bf16(af[r], bf, acc[r][cc], 0, 0, 0);
            }
        }

        // ---- pre-scale rows by out_norm (z' = D_out z), in place ----
        #pragma unroll
        for (int r=0;r<4;r++){
            #pragma unroll
            for (int q=0;q<4;q++){
                float so = s_onr[r*16 + hi*4 + q];
                #pragma unroll
                for (int cc=0;cc<4;cc++) acc[r][cc][q] *= so;
            }
        }

        // ---- mix per cc-block: m[:,cc] = C @ z'[:,cc]  (low reg pressure) ----
        // zf(ks) elem j = z'[ks*32+(j>>2)*16+hi*4+(j&3)][cc*16+lr] = acc[ks*2+(j>>2)][cc][j&3]
        #pragma unroll
        for (int cc=0;cc<4;cc++){
            s16x8 zf0, zf1;
            zf0[0]=(short)f2bf(acc[0][cc][0]); zf0[1]=(short)f2bf(acc[0][cc][1]);
            zf0[2]=(short)f2bf(acc[0][cc][2]); zf0[3]=(short)f2bf(acc[0][cc][3]);
            zf0[4]=(short)f2bf(acc[1][cc][0]); zf0[5]=(short)f2bf(acc[1][cc][1]);
            zf0[6]=(short)f2bf(acc[1][cc][2]); zf0[7]=(short)f2bf(acc[1][cc][3]);
            zf1[0]=(short)f2bf(acc[2][cc][0]); zf1[1]=(short)f2bf(acc[2][cc][1]);
            zf1[2]=(short)f2bf(acc[2][cc][2]); zf1[3]=(short)f2bf(acc[2][cc][3]);
            zf1[4]=(short)f2bf(acc[3][cc][0]); zf1[5]=(short)f2bf(acc[3][cc][1]);
            zf1[6]=(short)f2bf(acc[3][cc][2]); zf1[7]=(short)f2bf(acc[3][cc][3]);
            #pragma unroll
            for (int ro=0; ro<4; ro++){
                s16x8 cf0 = *reinterpret_cast<const s16x8*>(Cpack + ((ro*2+0)*64 + lane)*8);
                s16x8 cf1 = *reinterpret_cast<const s16x8*>(Cpack + ((ro*2+1)*64 + lane)*8);
                f32x4 m; m[0]=0.f; m[1]=0.f; m[2]=0.f; m[3]=0.f;
                m = __builtin_amdgcn_mfma_f32_16x16x32_bf16(cf1, zf1, m, 0, 0, 0);
                m = __builtin_amdgcn_mfma_f32_16x16x32_bf16(cf0, zf0, m, 0, 0, 0);
                acc[ro][cc] = m;
            }
        }

        // ---- post-scale by in_norm + bias ----
        const float* bias = bs + L*RANK;
        const float* gmp  = gam + L*RANK;
        const float* btp  = bet + L*RANK;
        float b4[4], g4[4], bt4[4];
        #pragma unroll
        for (int cc=0;cc<4;cc++){
            int col = w*64 + cc*16 + lr;
            b4[cc] = bias[col]; g4[cc] = gmp[col]; bt4[cc] = btp[col];
        }
        #pragma unroll
        for (int ro=0;ro<4;ro++){
            #pragma unroll
            for (int q=0;q<4;q++){
                float si = s_inr[ro*16 + hi*4 + q];
                #pragma unroll
                for (int cc=0;cc<4;cc++) acc[ro][cc][q] = acc[ro][cc][q]*si + b4[cc];
            }
        }

        // ---- LN over feature dim ----
        #pragma unroll
        for (int r=0;r<4;r++){
            #pragma unroll
            for (int q=0;q<4;q++){
                int row = r*16 + hi*4 + q;
                float s=0.f, qq=0.f;
                #pragma unroll
                for (int cc=0;cc<4;cc++){ float x = acc[r][cc][q]; s += x; qq += x*x; }
                #pragma unroll
                for (int mm=1;mm<16;mm<<=1){ s += __shfl_xor(s, mm); qq += __shfl_xor(qq, mm); }
                if (lr==0 && row < NROW){ red_s[row*8+w]=s; red_q[row*8+w]=qq; }
            }
        }
        __syncthreads();
        if (t < NROW){
            float s=0.f, qq=0.f;
            #pragma unroll
            for (int i=0;i<8;i++){ s += red_s[t*8+i]; qq += red_q[t*8+i]; }
            float mu = s * (1.f/RANK);
            float var = qq*(1.f/RANK) - mu*mu;
            s_mu[t] = mu; s_rs[t] = rsqrtf(var + LEPS);
        }
        __syncthreads();
        #pragma unroll
        for (int r=0;r<4;r++){
            #pragma unroll
            for (int q=0;q<4;q++){
                int row = r*16 + hi*4 + q;
                if (row < NROW){
                    float mu = s_mu[row], rs = s_rs[row];
                    #pragma unroll
                    for (int cc=0;cc<4;cc++){
                        int col = w*64 + cc*16 + lr;
                        float y = (acc[r][cc][q]-mu)*rs*g4[cc] + bt4[cc];
                        y = fmaxf(y, 0.f);
                        h[row*RANK + (((col>>3)^(row&7))*8) + (col&7)] = f2bf(y);
                    }
                }
            }
        }
        __syncthreads();
    }

    // ================= layer 3: only node 0 per graph =================
    // magg[g][col] = inorm0 * sum_s C[g][0][s]*onorm[s]*h2[g*9+s][col]
    float mgA[4], mgB[4];
    #pragma unroll
    for (int it=0; it<4; it++){
        int task = t + it*512;
        float a0=0.f, a1=0.f;
        if (task < GPB*256){
            int r = task >> 8, k2 = (task & 255)*2;
            #pragma unroll
            for (int s=0;s<9;s++){
                int srow = r*9 + s;
                u32 v = *reinterpret_cast<const u32*>(
                    h + srow*RANK + (((k2>>3)^(srow&7))*8) + (k2&7));
                float wA = s_C[r*81 + s] * s_onr[srow];
                a0 += wA * bf2f((u16)(v & 0xffffu));
                a1 += wA * bf2f((u16)(v >> 16));
            }
            float fin = s_inr[r*9];
            a0 *= fin; a1 *= fin;
        }
        mgA[it] = a0; mgB[it] = a1;
    }
    __syncthreads();                               // all h reads done
    #pragma unroll
    for (int it=0; it<4; it++){
        int task = t + it*512;
        if (task < GPB*256){
            int r = task >> 8, k2 = (task & 255)*2;
            u32 ov = (u32)f2bf(mgA[it]) | ((u32)f2bf(mgB[it])<<16);
            *reinterpret_cast<u32*>(h + r*RANK + (((k2>>3)^(r&7))*8) + (k2&7)) = ov;
        }
    }
    for (int idx = t; idx < 9*64; idx += 512){     // zero rows 7..15
        int rowz = 7 + (idx>>6), slot = idx & 63;
        uint4 zz; zz.x=0; zz.y=0; zz.z=0; zz.w=0;
        *reinterpret_cast<uint4*>(h + rowz*RANK + ((slot^(rowz&7))*8)) = zz;
    }
    __syncthreads();

    // z3 = magg @ W3 : single-tile GEMM (rows 0..6 real, 7..15 zero)
    const u16* Wp3 = Wp + (size_t)2*262144;
    f32x4 acc3[4];
    #pragma unroll
    for (int cc=0;cc<4;cc++)
        #pragma unroll
        for (int q=0;q<4;q++) acc3[cc][q] = 0.f;
    #pragma unroll 4
    for (int ks=0; ks<16; ks++){
        s16x8 af0 = *reinterpret_cast<const s16x8*>(
            h + lr*RANK + (((ks*4+hi)^(lr&7))*8));
        #pragma unroll
        for (int cc=0;cc<4;cc++){
            s16x8 bf = *reinterpret_cast<const s16x8*>(
                Wp3 + (size_t)(((ks*32 + (w*4+cc))*64 + lane)*8));
            acc3[cc] = __builtin_amdgcn_mfma_f32_16x16x32_bf16(af0, bf, acc3[cc], 0, 0, 0);
        }
    }
    float b3[4], g3[4], bt3[4];
    #pragma unroll
    for (int cc=0;cc<4;cc++){
        int col = w*64 + cc*16 + lr;
        b3[cc] = bs[2*RANK+col]; g3[cc] = gam[2*RANK+col]; bt3[cc] = bet[2*RANK+col];
    }
    #pragma unroll
    for (int cc=0;cc<4;cc++)
        #pragma unroll
        for (int q=0;q<4;q++) acc3[cc][q] += b3[cc];

    // LN over rows 0..6
    #pragma unroll
    for (int q=0;q<4;q++){
        int row = hi*4 + q;
        float s=0.f, qq=0.f;
        #pragma unroll
        for (int cc=0;cc<4;cc++){ float x = acc3[cc][q]; s += x; qq += x*x; }
        #pragma unroll
        for (int mm=1;mm<16;mm<<=1){ s += __shfl_xor(s, mm); qq += __shfl_xor(qq, mm); }
        if (lr==0 && row < GPB){ red_s[row*8+w]=s; red_q[row*8+w]=qq; }
    }
    __syncthreads();
    if (t < GPB){
        float s=0.f, qq=0.f;
        #pragma unroll
        for (int i=0;i<8;i++){ s += red_s[t*8+i]; qq += red_q[t*8+i]; }
        float mu = s * (1.f/RANK);
        float var = qq*(1.f/RANK) - mu*mu;
        s_mu[t] = mu; s_rs[t] = rsqrtf(var + LEPS);
    }
    __syncthreads();
    // dot with w_out
    #pragma unroll
    for (int q=0;q<4;q++){
        int row = hi*4 + q;
        float p = 0.f;
        if (row < GPB){
            float mu = s_mu[row], rs = s_rs[row];
            #pragma unroll
            for (int cc=0;cc<4;cc++){
                int col = w*64 + cc*16 + lr;
                float y = (acc3[cc][q]-mu)*rs*g3[cc] + bt3[cc];
                y = fmaxf(y, 0.f);
                p += y * w_out[col];
            }
        }
        #pragma unroll
        for (int mm=1;mm<16;mm<<=1) p += __shfl_xor(p, mm);
        if (lr==0 && row < GPB) red_s[row*8+w] = p;
    }
    __syncthreads();
    if (t < GPB){
        float sum = 0.f;
        #pragma unroll
        for (int i=0;i<8;i++) sum += red_s[t*8+i];
        int g = g0 + t;
        if (g < BGRAPH) out[g] = sum + b_out[0];
    }
}

extern "C" void kernel_launch(void* const* d_in, const int* in_sizes, int n_in,
                              void* d_out, int out_size, void* d_ws, size_t ws_size,
                              hipStream_t stream){
    (void)in_sizes; (void)n_in; (void)out_size; (void)ws_size;
    const int*   feat  = (const int*)d_in[0];
    const int*   src   = (const int*)d_in[1];
    const int*   dst   = (const int*)d_in[2];
    const float* emb   = (const float*)d_in[3];
    const float* Ws    = (const float*)d_in[4];
    const float* bs    = (const float*)d_in[5];
    const float* gam   = (const float*)d_in[6];
    const float* bet   = (const float*)d_in[7];
    const float* w_out = (const float*)d_in[8];
    const float* b_out = (const float*)d_in[9];
    float* out = (float*)d_out;

    u16* Wp = (u16*)d_ws;   // 1.5 MB — proven-safe ws footprint

    k_repack<<<dim3(3*RANK*RANK/256), dim3(256), 0, stream>>>(Ws, Wp);
    k_fused<<<dim3(NBLK), dim3(512), 0, stream>>>(feat, src, dst, emb, Wp,
        bs, gam, bet, w_out, b_out, out);
}